// Round 11
// baseline (240.768 us; speedup 1.0000x reference)
//
#include <hip/hip_runtime.h>

typedef _Float16 f16x2 __attribute__((ext_vector_type(2)));
typedef _Float16 f16x4 __attribute__((ext_vector_type(4)));
typedef _Float16 f16x8 __attribute__((ext_vector_type(8)));
typedef float    f32x4 __attribute__((ext_vector_type(4)));
typedef float    f32x16 __attribute__((ext_vector_type(16)));
typedef unsigned uint32x2 __attribute__((ext_vector_type(2)));

#define LOG2E_F 1.44269504088896340736f
#define AS1 __attribute__((address_space(1)))
#define AS3 __attribute__((address_space(3)))

namespace {
constexpr int kC     = 256;
constexpr int kN     = 4096;
constexpr int kQB    = 128;
constexpr int kKVB   = 64;
constexpr int kSteps = kN / kKVB;
constexpr size_t kImgStride = 2097152;   // 2 MB per (b,m) K-image
constexpr size_t kVImgBase  = 16777216;  // V-images at +16 MB
// LDS: K double buffer 2x32K @0 | V TRIPLE buffer 3x32K @64K = 160 KiB exactly.
// Epilogue overlays: A (128K) @0, Mb/Lb inside the V2 region.
constexpr int kVBase  = 65536;
constexpr int MB_OFF  = 131072;
constexpr int LB_OFF  = 131584;
constexpr int LDS_BYTES = 163840;
}

__device__ __forceinline__ int swz8(int r) { return (r ^ (r >> 3)) & 7; }
// K tile: c-major granules: [c8 32][j 64] x 16B. A wave's fragment read
// (li varies, c8 fixed) hits 32 consecutive granules -> conflict-free.
__device__ __forceinline__ int kbl(int j, int c) {
  return (c >> 3) * 1024 + j * 16 + ((c & 7) << 1);
}
// V tile: [c 256][j 64] f16, rows 128 B = 8 slots x 16B (measured conflict-free)
__device__ __forceinline__ int vbl(int c, int j) {
  return c * 128 + ((((j >> 3) ^ swz8(c)) << 4) | ((j & 7) << 1));
}

__device__ __forceinline__ void glds16(const void* g, void* l) {
  __builtin_amdgcn_global_load_lds((AS1 const unsigned int*)g,
                                   (AS3 unsigned int*)l, 16, 0, 0);
}

// xor-32 butterfly halves via the SSA-pure builtin (both post-swap registers).
__device__ __forceinline__ void xor32_halves(float x, float& a, float& c) {
  union { float f; unsigned u; } ux; ux.f = x;
  uint32x2 r = __builtin_amdgcn_permlane32_swap(ux.u, ux.u, false, false);
  union { unsigned u; float f; } ra, rc;
  ra.u = r[0]; rc.u = r[1];
  a = ra.f; c = rc.f;
}

// ============ pre-pass: f32 [C][N] -> pre-swizzled f16 K-image + V-image ======
__global__ __launch_bounds__(256)
void convert_images(const float* __restrict__ Vp, const float* __restrict__ Tp,
                    char* __restrict__ ws) {
  __shared__ alignas(16) char clds[65536];  // K-copy 32K | V-copy 32K
  const int bm   = blockIdx.x >> 6;   // b*2 + m  (m: 0=V, 1=T)
  const int tile = blockIdx.x & 63;
  const int tid  = threadIdx.x;
  const float* src = ((bm & 1) ? Tp : Vp) + (size_t)(bm >> 1) * kC * kN;

#pragma unroll
  for (int it = 0; it < 16; ++it) {
    const int c  = it * 16 + (tid >> 4);
    const int jf = (tid & 15) * 4;
    const float4 v = *(const float4*)(src + (size_t)c * kN + tile * 64 + jf);
    _Float16 h0 = (_Float16)v.x, h1 = (_Float16)v.y;
    _Float16 h2 = (_Float16)v.z, h3 = (_Float16)v.w;
    f16x4 hv; hv[0] = h0; hv[1] = h1; hv[2] = h2; hv[3] = h3;
    *(f16x4*)(clds + 32768 + vbl(c, jf)) = hv;          // V-copy (8B, aligned)
    *(_Float16*)(clds + kbl(jf + 0, c)) = h0;           // K-copy scalar
    *(_Float16*)(clds + kbl(jf + 1, c)) = h1;
    *(_Float16*)(clds + kbl(jf + 2, c)) = h2;
    *(_Float16*)(clds + kbl(jf + 3, c)) = h3;
  }
  __syncthreads();
  char* kout = ws + (size_t)bm * kImgStride + (size_t)tile * 32768;
  char* vout = ws + kVImgBase + (size_t)bm * kImgStride + (size_t)tile * 32768;
#pragma unroll
  for (int k = 0; k < 8; ++k) {
    const int off = k * 4096 + tid * 16;
    *(uint4*)(kout + off) = *(const uint4*)(clds + off);
    *(uint4*)(vout + off) = *(const uint4*)(clds + 32768 + off);
  }
}

// ============ main fused attention kernel =====================================
__global__ __launch_bounds__(512, 2)
void mutual_attn_fused(const float* __restrict__ Vp,
                       const float* __restrict__ Tp,
                       const char* __restrict__ ws,
                       float* __restrict__ outp) {
  __shared__ alignas(16) char lds[LDS_BYTES];

  const int tid = threadIdx.x;
  const int w   = tid >> 6;
  const int l   = tid & 63;
  const int li  = l & 31;
  const int g   = l >> 5;
  const int qw  = w & 3;        // i-quadrant (32 rows each)
  const int h   = w >> 2;       // j-half owner (32 j each)

  const int bid = blockIdx.x;
  const int dir = bid & 1;
  const int b   = (bid >> 1) & 3;
  const int qt  = bid >> 3;
  const int i0  = qt * kQB;

  const float* Qg = (dir ? Tp : Vp) + (size_t)b * kC * kN;  // base-add source
  const int bmK = b * 2 + (dir ? 0 : 1);
  const int bmQ = b * 2 + (dir ? 1 : 0);
  const char* KimgK = ws + (size_t)bmK * kImgStride;
  const char* VimgK = ws + kVImgBase + (size_t)bmK * kImgStride;
  const char* KimgQ = ws + (size_t)bmQ * kImgStride;

  auto issue_glds = [&](int t) {  // stage tile t: K->K[t&1], V->V[t%3]
    const char* gk = KimgK + (size_t)t * 32768;
    const char* gv = VimgK + (size_t)t * 32768;
    char* lk = lds + (t & 1) * 32768;
    char* lv = lds + kVBase + (t % 3) * 32768;
    const int off0 = w * 4096 + l * 16;
#pragma unroll
    for (int k = 0; k < 4; ++k) {
      glds16(gk + off0 + k * 1024, lk + off0 + k * 1024);
      glds16(gv + off0 + k * 1024, lv + off0 + k * 1024);
    }
  };

  // ---- stage tile 0 (async HW copy), then gather Q into registers
  issue_glds(0);

  const int iq = i0 + 32 * qw + li;
  const char* qsrc = KimgQ + (size_t)(iq >> 6) * 32768;
  const int jq = iq & 63;
  f16x8 qreg[16];
#pragma unroll
  for (int kc = 0; kc < 16; ++kc)
    qreg[kc] = *(const f16x8*)(qsrc + kbl(jq, kc * 16 + 8 * g));

  float Mrow = -1e30f;
  float Lrow = 0.0f;
  f32x16 oacc[8];
#pragma unroll
  for (int cf = 0; cf < 8; ++cf)
#pragma unroll
    for (int r = 0; r < 16; ++r) oacc[cf][r] = 0.0f;

  f16x8 pa0, pa1;   // P fragments of the previous step (consumed next iter)

  auto softmax_step = [&](f32x16& s0, f32x16& s1) {
    float p[16];
#pragma unroll
    for (int r = 0; r < 16; ++r) p[r] = s0[r] + s1[r];
    // v_max3-friendly reduction tree (value-exact vs pairwise)
    float m0 = fmaxf(fmaxf(p[0],  p[1]),  p[2]);
    float m1 = fmaxf(fmaxf(p[3],  p[4]),  p[5]);
    float m2 = fmaxf(fmaxf(p[6],  p[7]),  p[8]);
    float m3 = fmaxf(fmaxf(p[9],  p[10]), p[11]);
    float m4 = fmaxf(fmaxf(p[12], p[13]), p[14]);
    float mt = fmaxf(fmaxf(fmaxf(m0, m1), m2), fmaxf(fmaxf(m3, m4), p[15]));
    {
      float a, c; xor32_halves(mt, a, c);
      mt = fmaxf(a, c);              // == fmaxf(mt, __shfl_xor(mt, 32))
    }
    const bool  upd  = !__all(mt <= Mrow + 8.0f);     // defer-max
    const float Mnew = upd ? fmaxf(Mrow, mt) : Mrow;
    const float scl  = upd ? exp2f((Mrow - Mnew) * LOG2E_F) : 1.0f;
    Mrow = Mnew;
    const float mb = Mnew * LOG2E_F;
#pragma unroll
    for (int r = 0; r < 16; ++r) p[r] = exp2f(p[r] * LOG2E_F - mb);
    float ps = ((p[0] + p[1]) + (p[2] + p[3])) + ((p[4] + p[5]) + (p[6] + p[7]))
             + ((p[8] + p[9]) + (p[10] + p[11])) + ((p[12] + p[13]) + (p[14] + p[15]));
    {
      float a, c; xor32_halves(ps, a, c);
      ps = a + c;                    // == ps + __shfl_xor(ps, 32)
    }
    Lrow = Lrow * scl + ps;
    if (upd) {
#pragma unroll
      for (int r = 0; r < 16; ++r) {
        const float so = __shfl(scl, 4 * g + (r & 3) + 8 * (r >> 2));
#pragma unroll
        for (int cf = 0; cf < 8; ++cf) oacc[cf][r] *= so;
      }
    }
#pragma unroll
    for (int kj = 0; kj < 2; ++kj) {
      union { f16x2 h2; unsigned u; } w0, w1, w2, w3;
      w0.h2 = (f16x2){(_Float16)p[kj * 8 + 0], (_Float16)p[kj * 8 + 1]};
      w1.h2 = (f16x2){(_Float16)p[kj * 8 + 2], (_Float16)p[kj * 8 + 3]};
      w2.h2 = (f16x2){(_Float16)p[kj * 8 + 4], (_Float16)p[kj * 8 + 5]};
      w3.h2 = (f16x2){(_Float16)p[kj * 8 + 6], (_Float16)p[kj * 8 + 7]};
      asm volatile("v_permlane32_swap_b32 %0, %1" : "+v"(w0.u), "+v"(w2.u));
      asm volatile("v_permlane32_swap_b32 %0, %1" : "+v"(w1.u), "+v"(w3.u));
      union { unsigned u[4]; f16x8 v; } pk;
      pk.u[0] = w0.u; pk.u[1] = w1.u; pk.u[2] = w2.u; pk.u[3] = w3.u;
      if (kj == 0) pa0 = pk.v; else pa1 = pk.v;
    }
  };

  // ======== peeled step 0: QK only ========
  asm volatile("s_waitcnt vmcnt(0)" ::: "memory");
  __syncthreads();
  issue_glds(1);                 // K[1], V[1]: untouched buffers, no hazard
  {
    f32x16 s0, s1;
#pragma unroll
    for (int r = 0; r < 16; ++r) { s0[r] = 0.0f; s1[r] = 0.0f; }
#pragma unroll
    for (int kc2 = 0; kc2 < 8; ++kc2) {
      const int c0 = kc2 * 32 + 8 * g;
      const f16x8 kf0 = *(const f16x8*)(lds + kbl(32 * h + li, c0));
      const f16x8 kf1 = *(const f16x8*)(lds + kbl(32 * h + li, c0 + 16));
      s0 = __builtin_amdgcn_mfma_f32_32x32x16_f16(kf0, qreg[2 * kc2],     s0, 0, 0, 0);
      s1 = __builtin_amdgcn_mfma_f32_32x32x16_f16(kf1, qreg[2 * kc2 + 1], s1, 0, 0, 0);
    }
    softmax_step(s0, s1);
  }

  // ======== main loop s = 1..63: ONE barrier/step, QK(s) ∥ PV(s-1) ========
#pragma unroll 1
  for (int s = 1; s < kSteps; ++s) {
    asm volatile("s_waitcnt vmcnt(0)" ::: "memory");
    __syncthreads();             // tile s resident; buffers (s+1) are >=2 steps dead
    if (s + 1 < kSteps) issue_glds(s + 1);   // early issue: full step covers DMA

    const int curK = (s & 1) * 32768;
    const int oldV = kVBase + ((s - 1) % 3) * 32768;

    f32x16 s0, s1;
#pragma unroll
    for (int r = 0; r < 16; ++r) { s0[r] = 0.0f; s1[r] = 0.0f; }

    __builtin_amdgcn_s_setprio(1);
#pragma unroll
    for (int kc2 = 0; kc2 < 8; ++kc2) {
      const int c0  = kc2 * 32 + 8 * g;
      const int kj  = kc2 >> 2;                 // 0 for kc2<4, 1 else
      const int cf0 = (2 * kc2) & 7, cf1 = (2 * kc2 + 1) & 7;
      const int jb  = 32 * h + 16 * kj + 8 * g;
      const f16x8 kf0 = *(const f16x8*)(lds + curK + kbl(32 * h + li, c0));
      const f16x8 kf1 = *(const f16x8*)(lds + curK + kbl(32 * h + li, c0 + 16));
      const f16x8 vf0 = *(const f16x8*)(lds + oldV + vbl(32 * cf0 + li, jb));
      const f16x8 vf1 = *(const f16x8*)(lds + oldV + vbl(32 * cf1 + li, jb));
      s0 = __builtin_amdgcn_mfma_f32_32x32x16_f16(kf0, qreg[2 * kc2],     s0, 0, 0, 0);
      s1 = __builtin_amdgcn_mfma_f32_32x32x16_f16(kf1, qreg[2 * kc2 + 1], s1, 0, 0, 0);
      if (kj == 0) {
        oacc[cf0] = __builtin_amdgcn_mfma_f32_32x32x16_f16(pa0, vf0, oacc[cf0], 0, 0, 0);
        oacc[cf1] = __builtin_amdgcn_mfma_f32_32x32x16_f16(pa0, vf1, oacc[cf1], 0, 0, 0);
      } else {
        oacc[cf0] = __builtin_amdgcn_mfma_f32_32x32x16_f16(pa1, vf0, oacc[cf0], 0, 0, 0);
        oacc[cf1] = __builtin_amdgcn_mfma_f32_32x32x16_f16(pa1, vf1, oacc[cf1], 0, 0, 0);
      }
    }
    // Emission pin (T19): interleave 4-read groups with 4-MFMA groups so the
    // LDS queue stays shallow instead of one 32-read convoy after the barrier.
    // Scheduling-only; dependencies still enforced by the compiler.
#pragma unroll
    for (int t = 0; t < 8; ++t) {
      __builtin_amdgcn_sched_group_barrier(0x100, 4, 0);  // 4 DS_READ
      __builtin_amdgcn_sched_group_barrier(0x008, 4, 0);  // 4 MFMA
    }
    __builtin_amdgcn_s_setprio(0);

    softmax_step(s0, s1);        // overlaps the in-flight glds
  }

  // ======== tail: PV(63) ========
  {
    const int oldV = kVBase + ((kSteps - 1) % 3) * 32768;
#pragma unroll
    for (int kj = 0; kj < 2; ++kj) {
      const int jb = 32 * h + 16 * kj + 8 * g;
      const f16x8 pf = kj ? pa1 : pa0;
#pragma unroll
      for (int cf = 0; cf < 8; ++cf) {
        const f16x8 vf = *(const f16x8*)(lds + oldV + vbl(32 * cf + li, jb));
        oacc[cf] = __builtin_amdgcn_mfma_f32_32x32x16_f16(pf, vf, oacc[cf], 0, 0, 0);
      }
    }
  }
  __syncthreads();                 // all PV reads done before overlay reuse

  // ======== epilogue: merge j-halves (M,L,O), normalize, add base, store ======
  float* A  = (float*)lds;         // overlay [qw 4][c 256][i 32] f32 = 128KB
  float* Mb = (float*)(lds + MB_OFF);          // [128] (inside V2 region)
  float* Lb = (float*)(lds + LB_OFF);          // [128]
#define AOFF(qw_, c_, i_) \
  ((qw_) * 8192 + (c_) * 32 + (((((i_) >> 2) ^ ((c_) & 7)) << 2) | ((i_) & 3)))

  if (h == 1) {
#pragma unroll
    for (int r = 0; r < 16; ++r) {
      const int iL = 4 * g + (r & 3) + 8 * (r >> 2);
#pragma unroll
      for (int cf = 0; cf < 8; ++cf)
        A[AOFF(qw, 32 * cf + li, iL)] = oacc[cf][r];
    }
    if (g == 0) { Mb[qw * 32 + li] = Mrow; Lb[qw * 32 + li] = Lrow; }
  }
  __syncthreads();
  if (h == 0) {
    const float M1  = Mb[qw * 32 + li];
    const float L1  = Lb[qw * 32 + li];
    const float Mj  = fmaxf(Mrow, M1);
    const float d0  = exp2f((Mrow - Mj) * LOG2E_F);
    const float d1  = exp2f((M1 - Mj) * LOG2E_F);
    const float invL = 1.0f / (Lrow * d0 + L1 * d1);
#pragma unroll
    for (int r = 0; r < 16; ++r) {
      const int iL = 4 * g + (r & 3) + 8 * (r >> 2);
      const float sd0 = __shfl(d0 * invL, iL);
      const float sd1 = __shfl(d1 * invL, iL);
#pragma unroll
      for (int cf = 0; cf < 8; ++cf) {
        const int off = AOFF(qw, 32 * cf + li, iL);
        A[off] = oacc[cf][r] * sd0 + A[off] * sd1;
      }
    }
  }
  __syncthreads();
#undef AOFF
  {
    float* op = outp + ((size_t)b * 512 + dir * 256) * kN;
#pragma unroll
    for (int it = 0; it < 16; ++it) {
      const int n    = it * 512 + tid;
      const int slot = n & 7;           // logical i-chunk
      const int cq   = (n >> 3) & 255;
      const int qw4  = n >> 11;
      const f32x4 ov = *(const f32x4*)(lds + (qw4 * 8192 + cq * 32 +
                                              ((slot ^ (cq & 7)) << 2)) * 4);
      const int col = i0 + qw4 * 32 + slot * 4;
      const float4 bv = *(const float4*)(Qg + (size_t)cq * kN + col);
      float4 r4;
      r4.x = ov[0] + bv.x; r4.y = ov[1] + bv.y;
      r4.z = ov[2] + bv.z; r4.w = ov[3] + bv.w;
      *(float4*)(op + (size_t)cq * kN + col) = r4;
    }
  }
}

extern "C" void kernel_launch(void* const* d_in, const int* in_sizes, int n_in,
                              void* d_out, int out_size, void* d_ws, size_t ws_size,
                              hipStream_t stream) {
  const float* V = (const float*)d_in[0];
  const float* T = (const float*)d_in[1];
  float* out = (float*)d_out;
  char* ws = (char*)d_ws;
  (void)in_sizes; (void)n_in; (void)out_size; (void)ws_size;
  hipLaunchKernelGGL(convert_images, dim3(512), dim3(256), 0, stream, V, T, ws);
  hipLaunchKernelGGL(mutual_attn_fused, dim3(256), dim3(512), 0, stream,
                     V, T, (const char*)ws, out);
}

// Round 12
// 234.553 us; speedup vs baseline: 1.0265x; 1.0265x over previous
//
#include <hip/hip_runtime.h>

typedef _Float16 f16x2 __attribute__((ext_vector_type(2)));
typedef _Float16 f16x4 __attribute__((ext_vector_type(4)));
typedef _Float16 f16x8 __attribute__((ext_vector_type(8)));
typedef float    f32x4 __attribute__((ext_vector_type(4)));
typedef float    f32x16 __attribute__((ext_vector_type(16)));
typedef unsigned uint32x2 __attribute__((ext_vector_type(2)));

#define LOG2E_F 1.44269504088896340736f
#define AS1 __attribute__((address_space(1)))
#define AS3 __attribute__((address_space(3)))

namespace {
constexpr int kC     = 256;
constexpr int kN     = 4096;
constexpr int kQB    = 128;
constexpr int kKVB   = 64;
constexpr int kSteps = kN / kKVB;
constexpr size_t kImgStride = 2097152;   // 2 MB per (b,m) K-image
constexpr size_t kVImgBase  = 16777216;  // V-images at +16 MB
// LDS: K double buffer 2x32K @0 | V TRIPLE buffer 3x32K @64K = 160 KiB exactly.
// Epilogue overlays: A (128K) @0, Mb/Lb inside the V2 region.
constexpr int kVBase  = 65536;
constexpr int MB_OFF  = 131072;
constexpr int LB_OFF  = 131584;
constexpr int LDS_BYTES = 163840;
}

__device__ __forceinline__ int swz8(int r) { return (r ^ (r >> 3)) & 7; }
// K tile: c-major granules: [c8 32][j 64] x 16B. A wave's fragment read
// (li varies, c8 fixed) hits 32 consecutive granules -> conflict-free.
__device__ __forceinline__ int kbl(int j, int c) {
  return (c >> 3) * 1024 + j * 16 + ((c & 7) << 1);
}
// V tile: [c 256][j 64] f16, rows 128 B = 8 slots x 16B (measured conflict-free)
__device__ __forceinline__ int vbl(int c, int j) {
  return c * 128 + ((((j >> 3) ^ swz8(c)) << 4) | ((j & 7) << 1));
}

__device__ __forceinline__ void glds16(const void* g, void* l) {
  __builtin_amdgcn_global_load_lds((AS1 const unsigned int*)g,
                                   (AS3 unsigned int*)l, 16, 0, 0);
}

// xor-32 butterfly halves via the SSA-pure builtin (both post-swap registers).
__device__ __forceinline__ void xor32_halves(float x, float& a, float& c) {
  union { float f; unsigned u; } ux; ux.f = x;
  uint32x2 r = __builtin_amdgcn_permlane32_swap(ux.u, ux.u, false, false);
  union { unsigned u; float f; } ra, rc;
  ra.u = r[0]; rc.u = r[1];
  a = ra.f; c = rc.f;
}

// ============ pre-pass: f32 [C][N] -> pre-swizzled f16 K-image + V-image ======
__global__ __launch_bounds__(256)
void convert_images(const float* __restrict__ Vp, const float* __restrict__ Tp,
                    char* __restrict__ ws) {
  __shared__ alignas(16) char clds[65536];  // K-copy 32K | V-copy 32K
  const int bm   = blockIdx.x >> 6;   // b*2 + m  (m: 0=V, 1=T)
  const int tile = blockIdx.x & 63;
  const int tid  = threadIdx.x;
  const float* src = ((bm & 1) ? Tp : Vp) + (size_t)(bm >> 1) * kC * kN;

#pragma unroll
  for (int it = 0; it < 16; ++it) {
    const int c  = it * 16 + (tid >> 4);
    const int jf = (tid & 15) * 4;
    const float4 v = *(const float4*)(src + (size_t)c * kN + tile * 64 + jf);
    _Float16 h0 = (_Float16)v.x, h1 = (_Float16)v.y;
    _Float16 h2 = (_Float16)v.z, h3 = (_Float16)v.w;
    f16x4 hv; hv[0] = h0; hv[1] = h1; hv[2] = h2; hv[3] = h3;
    *(f16x4*)(clds + 32768 + vbl(c, jf)) = hv;          // V-copy (8B, aligned)
    *(_Float16*)(clds + kbl(jf + 0, c)) = h0;           // K-copy scalar
    *(_Float16*)(clds + kbl(jf + 1, c)) = h1;
    *(_Float16*)(clds + kbl(jf + 2, c)) = h2;
    *(_Float16*)(clds + kbl(jf + 3, c)) = h3;
  }
  __syncthreads();
  char* kout = ws + (size_t)bm * kImgStride + (size_t)tile * 32768;
  char* vout = ws + kVImgBase + (size_t)bm * kImgStride + (size_t)tile * 32768;
#pragma unroll
  for (int k = 0; k < 8; ++k) {
    const int off = k * 4096 + tid * 16;
    *(uint4*)(kout + off) = *(const uint4*)(clds + off);
    *(uint4*)(vout + off) = *(const uint4*)(clds + 32768 + off);
  }
}

// ============ main fused attention kernel =====================================
__global__ __launch_bounds__(512, 2)
void mutual_attn_fused(const float* __restrict__ Vp,
                       const float* __restrict__ Tp,
                       const char* __restrict__ ws,
                       float* __restrict__ outp) {
  __shared__ alignas(16) char lds[LDS_BYTES];

  const int tid = threadIdx.x;
  const int w   = tid >> 6;
  const int l   = tid & 63;
  const int li  = l & 31;
  const int g   = l >> 5;
  const int qw  = w & 3;        // i-quadrant (32 rows each)
  const int h   = w >> 2;       // j-half owner (32 j each)

  const int bid = blockIdx.x;
  const int dir = bid & 1;
  const int b   = (bid >> 1) & 3;
  const int qt  = bid >> 3;
  const int i0  = qt * kQB;

  const float* Qg = (dir ? Tp : Vp) + (size_t)b * kC * kN;  // base-add source
  const int bmK = b * 2 + (dir ? 0 : 1);
  const int bmQ = b * 2 + (dir ? 1 : 0);
  const char* KimgK = ws + (size_t)bmK * kImgStride;
  const char* VimgK = ws + kVImgBase + (size_t)bmK * kImgStride;
  const char* KimgQ = ws + (size_t)bmQ * kImgStride;

  auto issue_glds = [&](int t) {  // stage tile t: K->K[t&1], V->V[t%3]
    const char* gk = KimgK + (size_t)t * 32768;
    const char* gv = VimgK + (size_t)t * 32768;
    char* lk = lds + (t & 1) * 32768;
    char* lv = lds + kVBase + (t % 3) * 32768;
    const int off0 = w * 4096 + l * 16;
#pragma unroll
    for (int k = 0; k < 4; ++k) {
      glds16(gk + off0 + k * 1024, lk + off0 + k * 1024);
      glds16(gv + off0 + k * 1024, lv + off0 + k * 1024);
    }
  };

  // ---- stage tile 0 (async HW copy), then gather Q into registers
  issue_glds(0);

  const int iq = i0 + 32 * qw + li;
  const char* qsrc = KimgQ + (size_t)(iq >> 6) * 32768;
  const int jq = iq & 63;
  f16x8 qreg[16];
#pragma unroll
  for (int kc = 0; kc < 16; ++kc)
    qreg[kc] = *(const f16x8*)(qsrc + kbl(jq, kc * 16 + 8 * g));

  float Mrow = -1e30f;
  float Lrow = 0.0f;
  f32x16 oacc[8];
#pragma unroll
  for (int cf = 0; cf < 8; ++cf)
#pragma unroll
    for (int r = 0; r < 16; ++r) oacc[cf][r] = 0.0f;

  f16x8 pa0, pa1;   // P fragments of the previous step (consumed next iter)

  auto softmax_step = [&](f32x16& s0, f32x16& s1) {
    float p[16];
#pragma unroll
    for (int r = 0; r < 16; ++r) p[r] = s0[r] + s1[r];
    // v_max3-friendly reduction tree (value-exact vs pairwise)
    float m0 = fmaxf(fmaxf(p[0],  p[1]),  p[2]);
    float m1 = fmaxf(fmaxf(p[3],  p[4]),  p[5]);
    float m2 = fmaxf(fmaxf(p[6],  p[7]),  p[8]);
    float m3 = fmaxf(fmaxf(p[9],  p[10]), p[11]);
    float m4 = fmaxf(fmaxf(p[12], p[13]), p[14]);
    float mt = fmaxf(fmaxf(fmaxf(m0, m1), m2), fmaxf(fmaxf(m3, m4), p[15]));
    {
      float a, c; xor32_halves(mt, a, c);
      mt = fmaxf(a, c);              // == fmaxf(mt, __shfl_xor(mt, 32))
    }
    const bool  upd  = !__all(mt <= Mrow + 8.0f);     // defer-max
    const float Mnew = upd ? fmaxf(Mrow, mt) : Mrow;
    const float scl  = upd ? exp2f((Mrow - Mnew) * LOG2E_F) : 1.0f;
    Mrow = Mnew;
    const float mb = Mnew * LOG2E_F;
#pragma unroll
    for (int r = 0; r < 16; ++r) p[r] = exp2f(p[r] * LOG2E_F - mb);
    float ps = ((p[0] + p[1]) + (p[2] + p[3])) + ((p[4] + p[5]) + (p[6] + p[7]))
             + ((p[8] + p[9]) + (p[10] + p[11])) + ((p[12] + p[13]) + (p[14] + p[15]));
    {
      float a, c; xor32_halves(ps, a, c);
      ps = a + c;                    // == ps + __shfl_xor(ps, 32)
    }
    Lrow = Lrow * scl + ps;
    if (upd) {
#pragma unroll
      for (int r = 0; r < 16; ++r) {
        const float so = __shfl(scl, 4 * g + (r & 3) + 8 * (r >> 2));
#pragma unroll
        for (int cf = 0; cf < 8; ++cf) oacc[cf][r] *= so;
      }
    }
#pragma unroll
    for (int kj = 0; kj < 2; ++kj) {
      union { f16x2 h2; unsigned u; } w0, w1, w2, w3;
      w0.h2 = (f16x2){(_Float16)p[kj * 8 + 0], (_Float16)p[kj * 8 + 1]};
      w1.h2 = (f16x2){(_Float16)p[kj * 8 + 2], (_Float16)p[kj * 8 + 3]};
      w2.h2 = (f16x2){(_Float16)p[kj * 8 + 4], (_Float16)p[kj * 8 + 5]};
      w3.h2 = (f16x2){(_Float16)p[kj * 8 + 6], (_Float16)p[kj * 8 + 7]};
      asm volatile("v_permlane32_swap_b32 %0, %1" : "+v"(w0.u), "+v"(w2.u));
      asm volatile("v_permlane32_swap_b32 %0, %1" : "+v"(w1.u), "+v"(w3.u));
      union { unsigned u[4]; f16x8 v; } pk;
      pk.u[0] = w0.u; pk.u[1] = w1.u; pk.u[2] = w2.u; pk.u[3] = w3.u;
      if (kj == 0) pa0 = pk.v; else pa1 = pk.v;
    }
  };

  // ======== peeled step 0: QK only ========
  asm volatile("s_waitcnt vmcnt(0)" ::: "memory");
  __syncthreads();
  issue_glds(1);                 // K[1], V[1]: untouched buffers, no hazard
  {
    f32x16 s0, s1;
#pragma unroll
    for (int r = 0; r < 16; ++r) { s0[r] = 0.0f; s1[r] = 0.0f; }
#pragma unroll
    for (int kc2 = 0; kc2 < 8; ++kc2) {
      const int c0 = kc2 * 32 + 8 * g;
      const f16x8 kf0 = *(const f16x8*)(lds + kbl(32 * h + li, c0));
      const f16x8 kf1 = *(const f16x8*)(lds + kbl(32 * h + li, c0 + 16));
      s0 = __builtin_amdgcn_mfma_f32_32x32x16_f16(kf0, qreg[2 * kc2],     s0, 0, 0, 0);
      s1 = __builtin_amdgcn_mfma_f32_32x32x16_f16(kf1, qreg[2 * kc2 + 1], s1, 0, 0, 0);
    }
    softmax_step(s0, s1);
  }

  // ======== main loop s = 1..63: ONE barrier/step ========
  // Anti-phase ordering: SIMD k hosts waves k and k+4, which differ only in
  // h. QK(s) and PV(s-1) are independent phases, so h=0 waves run QK->PV and
  // h=1 waves run PV->QK: one wave's K-read/QK burst overlaps its SIMD
  // sibling's V-read/PV burst instead of colliding on the same pipes.
#pragma unroll 1
  for (int s = 1; s < kSteps; ++s) {
    asm volatile("s_waitcnt vmcnt(0)" ::: "memory");
    __syncthreads();             // tile s resident; buffers (s+1) are >=2 steps dead
    if (s + 1 < kSteps) issue_glds(s + 1);   // early issue: full step covers DMA

    const int curK = (s & 1) * 32768;
    const int oldV = kVBase + ((s - 1) % 3) * 32768;

    f32x16 s0, s1;
#pragma unroll
    for (int r = 0; r < 16; ++r) { s0[r] = 0.0f; s1[r] = 0.0f; }

    auto qk_phase = [&]() {
#pragma unroll
      for (int kc2 = 0; kc2 < 8; ++kc2) {
        const int c0 = kc2 * 32 + 8 * g;
        const f16x8 kf0 = *(const f16x8*)(lds + curK + kbl(32 * h + li, c0));
        const f16x8 kf1 = *(const f16x8*)(lds + curK + kbl(32 * h + li, c0 + 16));
        s0 = __builtin_amdgcn_mfma_f32_32x32x16_f16(kf0, qreg[2 * kc2],     s0, 0, 0, 0);
        s1 = __builtin_amdgcn_mfma_f32_32x32x16_f16(kf1, qreg[2 * kc2 + 1], s1, 0, 0, 0);
      }
    };
    auto pv_phase = [&]() {
#pragma unroll
      for (int kj = 0; kj < 2; ++kj) {
        const int jb = 32 * h + 16 * kj + 8 * g;
        const f16x8 pf = kj ? pa1 : pa0;
#pragma unroll
        for (int cf = 0; cf < 8; ++cf) {
          const f16x8 vf = *(const f16x8*)(lds + oldV + vbl(32 * cf + li, jb));
          oacc[cf] = __builtin_amdgcn_mfma_f32_32x32x16_f16(pf, vf, oacc[cf], 0, 0, 0);
        }
      }
    };

    __builtin_amdgcn_s_setprio(1);
    if (h == 0) { qk_phase(); pv_phase(); }
    else        { pv_phase(); qk_phase(); }
    __builtin_amdgcn_s_setprio(0);

    softmax_step(s0, s1);        // overlaps the in-flight glds
  }

  // ======== tail: PV(63) ========
  {
    const int oldV = kVBase + ((kSteps - 1) % 3) * 32768;
#pragma unroll
    for (int kj = 0; kj < 2; ++kj) {
      const int jb = 32 * h + 16 * kj + 8 * g;
      const f16x8 pf = kj ? pa1 : pa0;
#pragma unroll
      for (int cf = 0; cf < 8; ++cf) {
        const f16x8 vf = *(const f16x8*)(lds + oldV + vbl(32 * cf + li, jb));
        oacc[cf] = __builtin_amdgcn_mfma_f32_32x32x16_f16(pf, vf, oacc[cf], 0, 0, 0);
      }
    }
  }
  __syncthreads();                 // all PV reads done before overlay reuse

  // ======== epilogue: merge j-halves (M,L,O), normalize, add base, store ======
  float* A  = (float*)lds;         // overlay [qw 4][c 256][i 32] f32 = 128KB
  float* Mb = (float*)(lds + MB_OFF);          // [128] (inside V2 region)
  float* Lb = (float*)(lds + LB_OFF);          // [128]
#define AOFF(qw_, c_, i_) \
  ((qw_) * 8192 + (c_) * 32 + (((((i_) >> 2) ^ ((c_) & 7)) << 2) | ((i_) & 3)))

  if (h == 1) {
#pragma unroll
    for (int r = 0; r < 16; ++r) {
      const int iL = 4 * g + (r & 3) + 8 * (r >> 2);
#pragma unroll
      for (int cf = 0; cf < 8; ++cf)
        A[AOFF(qw, 32 * cf + li, iL)] = oacc[cf][r];
    }
    if (g == 0) { Mb[qw * 32 + li] = Mrow; Lb[qw * 32 + li] = Lrow; }
  }
  __syncthreads();
  if (h == 0) {
    const float M1  = Mb[qw * 32 + li];
    const float L1  = Lb[qw * 32 + li];
    const float Mj  = fmaxf(Mrow, M1);
    const float d0  = exp2f((Mrow - Mj) * LOG2E_F);
    const float d1  = exp2f((M1 - Mj) * LOG2E_F);
    const float invL = 1.0f / (Lrow * d0 + L1 * d1);
#pragma unroll
    for (int r = 0; r < 16; ++r) {
      const int iL = 4 * g + (r & 3) + 8 * (r >> 2);
      const float sd0 = __shfl(d0 * invL, iL);
      const float sd1 = __shfl(d1 * invL, iL);
#pragma unroll
      for (int cf = 0; cf < 8; ++cf) {
        const int off = AOFF(qw, 32 * cf + li, iL);
        A[off] = oacc[cf][r] * sd0 + A[off] * sd1;
      }
    }
  }
  __syncthreads();
#undef AOFF
  {
    float* op = outp + ((size_t)b * 512 + dir * 256) * kN;
#pragma unroll
    for (int it = 0; it < 16; ++it) {
      const int n    = it * 512 + tid;
      const int slot = n & 7;           // logical i-chunk
      const int cq   = (n >> 3) & 255;
      const int qw4  = n >> 11;
      const f32x4 ov = *(const f32x4*)(lds + (qw4 * 8192 + cq * 32 +
                                              ((slot ^ (cq & 7)) << 2)) * 4);
      const int col = i0 + qw4 * 32 + slot * 4;
      const float4 bv = *(const float4*)(Qg + (size_t)cq * kN + col);
      float4 r4;
      r4.x = ov[0] + bv.x; r4.y = ov[1] + bv.y;
      r4.z = ov[2] + bv.z; r4.w = ov[3] + bv.w;
      *(float4*)(op + (size_t)cq * kN + col) = r4;
    }
  }
}

extern "C" void kernel_launch(void* const* d_in, const int* in_sizes, int n_in,
                              void* d_out, int out_size, void* d_ws, size_t ws_size,
                              hipStream_t stream) {
  const float* V = (const float*)d_in[0];
  const float* T = (const float*)d_in[1];
  float* out = (float*)d_out;
  char* ws = (char*)d_ws;
  (void)in_sizes; (void)n_in; (void)out_size; (void)ws_size;
  hipLaunchKernelGGL(convert_images, dim3(512), dim3(256), 0, stream, V, T, ws);
  hipLaunchKernelGGL(mutual_attn_fused, dim3(256), dim3(512), 0, stream,
                     V, T, (const char*)ws, out);
}

// Round 14
// 219.529 us; speedup vs baseline: 1.0967x; 1.0684x over previous
//
#include <hip/hip_runtime.h>

typedef _Float16 f16x2 __attribute__((ext_vector_type(2)));
typedef _Float16 f16x4 __attribute__((ext_vector_type(4)));
typedef _Float16 f16x8 __attribute__((ext_vector_type(8)));
typedef float    f32x4 __attribute__((ext_vector_type(4)));
typedef float    f32x16 __attribute__((ext_vector_type(16)));
typedef unsigned uint32x2 __attribute__((ext_vector_type(2)));

#define LOG2E_F 1.44269504088896340736f
#define AS1 __attribute__((address_space(1)))
#define AS3 __attribute__((address_space(3)))

namespace {
constexpr int kC     = 256;
constexpr int kN     = 4096;
constexpr int kQB    = 128;
constexpr int kKVB   = 64;
constexpr int kSteps = kN / kKVB;
constexpr size_t kImgStride = 2097152;   // 2 MB per (b,m) K-image
constexpr size_t kVImgBase  = 16777216;  // V-images at +16 MB
// LDS: K double buffer 2x32K @0 | V TRIPLE buffer 3x32K @64K = 160 KiB exactly.
// Epilogue overlays: A (128K) @0, Mb/Lb inside the V2 region.
constexpr int kVBase  = 65536;
constexpr int MB_OFF  = 131072;
constexpr int LB_OFF  = 131584;
constexpr int LDS_BYTES = 163840;
}

__device__ __forceinline__ int swz8(int r) { return (r ^ (r >> 3)) & 7; }
// K tile: c-major granules: [c8 32][j 64] x 16B. A wave's fragment read
// (li varies, c8 fixed) hits 32 consecutive granules -> conflict-free.
__device__ __forceinline__ int kbl(int j, int c) {
  return (c >> 3) * 1024 + j * 16 + ((c & 7) << 1);
}
// V tile: [c 256][j 64] f16, rows 128 B = 8 slots x 16B (measured conflict-free)
__device__ __forceinline__ int vbl(int c, int j) {
  return c * 128 + ((((j >> 3) ^ swz8(c)) << 4) | ((j & 7) << 1));
}

__device__ __forceinline__ void glds16(const void* g, void* l) {
  __builtin_amdgcn_global_load_lds((AS1 const unsigned int*)g,
                                   (AS3 unsigned int*)l, 16, 0, 0);
}

// xor-32 butterfly halves via the SSA-pure builtin (both post-swap registers).
__device__ __forceinline__ void xor32_halves(float x, float& a, float& c) {
  union { float f; unsigned u; } ux; ux.f = x;
  uint32x2 r = __builtin_amdgcn_permlane32_swap(ux.u, ux.u, false, false);
  union { unsigned u; float f; } ra, rc;
  ra.u = r[0]; rc.u = r[1];
  a = ra.f; c = rc.f;
}

// ============ pre-pass: f32 [C][N] -> pre-swizzled f16 K-image + V-image ======
__global__ __launch_bounds__(256)
void convert_images(const float* __restrict__ Vp, const float* __restrict__ Tp,
                    char* __restrict__ ws) {
  __shared__ alignas(16) char clds[65536];  // K-copy 32K | V-copy 32K
  const int bm   = blockIdx.x >> 6;   // b*2 + m  (m: 0=V, 1=T)
  const int tile = blockIdx.x & 63;
  const int tid  = threadIdx.x;
  const float* src = ((bm & 1) ? Tp : Vp) + (size_t)(bm >> 1) * kC * kN;

#pragma unroll
  for (int it = 0; it < 16; ++it) {
    const int c  = it * 16 + (tid >> 4);
    const int jf = (tid & 15) * 4;
    const float4 v = *(const float4*)(src + (size_t)c * kN + tile * 64 + jf);
    _Float16 h0 = (_Float16)v.x, h1 = (_Float16)v.y;
    _Float16 h2 = (_Float16)v.z, h3 = (_Float16)v.w;
    f16x4 hv; hv[0] = h0; hv[1] = h1; hv[2] = h2; hv[3] = h3;
    *(f16x4*)(clds + 32768 + vbl(c, jf)) = hv;          // V-copy (8B, aligned)
    *(_Float16*)(clds + kbl(jf + 0, c)) = h0;           // K-copy scalar
    *(_Float16*)(clds + kbl(jf + 1, c)) = h1;
    *(_Float16*)(clds + kbl(jf + 2, c)) = h2;
    *(_Float16*)(clds + kbl(jf + 3, c)) = h3;
  }
  __syncthreads();
  char* kout = ws + (size_t)bm * kImgStride + (size_t)tile * 32768;
  char* vout = ws + kVImgBase + (size_t)bm * kImgStride + (size_t)tile * 32768;
#pragma unroll
  for (int k = 0; k < 8; ++k) {
    const int off = k * 4096 + tid * 16;
    *(uint4*)(kout + off) = *(const uint4*)(clds + off);
    *(uint4*)(vout + off) = *(const uint4*)(clds + 32768 + off);
  }
}

// ============ main fused attention kernel =====================================
__global__ __launch_bounds__(512, 2)
void mutual_attn_fused(const float* __restrict__ Vp,
                       const float* __restrict__ Tp,
                       const char* __restrict__ ws,
                       float* __restrict__ outp) {
  __shared__ alignas(16) char lds[LDS_BYTES];

  const int tid = threadIdx.x;
  const int w   = tid >> 6;
  const int l   = tid & 63;
  const int li  = l & 31;
  const int g   = l >> 5;
  const int qw  = w & 3;        // i-quadrant (32 rows each)
  const int h   = w >> 2;       // j-half owner (32 j each)

  const int bid = blockIdx.x;
  const int dir = bid & 1;
  const int b   = (bid >> 1) & 3;
  const int qt  = bid >> 3;
  const int i0  = qt * kQB;

  const float* Qg = (dir ? Tp : Vp) + (size_t)b * kC * kN;  // base-add source
  const int bmK = b * 2 + (dir ? 0 : 1);
  const int bmQ = b * 2 + (dir ? 1 : 0);
  const char* KimgK = ws + (size_t)bmK * kImgStride;
  const char* VimgK = ws + kVImgBase + (size_t)bmK * kImgStride;
  const char* KimgQ = ws + (size_t)bmQ * kImgStride;

  auto issue_glds = [&](int t) {  // stage tile t: K->K[t&1], V->V[t%3]
    const char* gk = KimgK + (size_t)t * 32768;
    const char* gv = VimgK + (size_t)t * 32768;
    char* lk = lds + (t & 1) * 32768;
    char* lv = lds + kVBase + (t % 3) * 32768;
    const int off0 = w * 4096 + l * 16;
#pragma unroll
    for (int k = 0; k < 4; ++k) {
      glds16(gk + off0 + k * 1024, lk + off0 + k * 1024);
      glds16(gv + off0 + k * 1024, lv + off0 + k * 1024);
    }
  };

  // ---- stage tile 0 (async HW copy), then gather Q into registers
  issue_glds(0);

  const int iq = i0 + 32 * qw + li;
  const char* qsrc = KimgQ + (size_t)(iq >> 6) * 32768;
  const int jq = iq & 63;
  f16x8 qreg[16];
#pragma unroll
  for (int kc = 0; kc < 16; ++kc)
    qreg[kc] = *(const f16x8*)(qsrc + kbl(jq, kc * 16 + 8 * g));

  float Mrow = -1e30f;
  float Lrow = 0.0f;
  f32x16 oacc[8];
#pragma unroll
  for (int cf = 0; cf < 8; ++cf)
#pragma unroll
    for (int r = 0; r < 16; ++r) oacc[cf][r] = 0.0f;

  f16x8 pa0, pa1;   // P fragments of the previous step (consumed next iter)

  auto softmax_step = [&](f32x16& s0, f32x16& s1) {
    float p[16];
#pragma unroll
    for (int r = 0; r < 16; ++r) p[r] = s0[r] + s1[r];
    // v_max3-friendly reduction tree (value-exact vs pairwise)
    float m0 = fmaxf(fmaxf(p[0],  p[1]),  p[2]);
    float m1 = fmaxf(fmaxf(p[3],  p[4]),  p[5]);
    float m2 = fmaxf(fmaxf(p[6],  p[7]),  p[8]);
    float m3 = fmaxf(fmaxf(p[9],  p[10]), p[11]);
    float m4 = fmaxf(fmaxf(p[12], p[13]), p[14]);
    float mt = fmaxf(fmaxf(fmaxf(m0, m1), m2), fmaxf(fmaxf(m3, m4), p[15]));
    {
      float a, c; xor32_halves(mt, a, c);
      mt = fmaxf(a, c);              // == fmaxf(mt, __shfl_xor(mt, 32))
    }
    const bool  upd  = !__all(mt <= Mrow + 8.0f);     // defer-max
    const float Mnew = upd ? fmaxf(Mrow, mt) : Mrow;
    const float scl  = upd ? exp2f((Mrow - Mnew) * LOG2E_F) : 1.0f;
    Mrow = Mnew;
    const float mb = Mnew * LOG2E_F;
#pragma unroll
    for (int r = 0; r < 16; ++r) p[r] = exp2f(p[r] * LOG2E_F - mb);
    float ps = ((p[0] + p[1]) + (p[2] + p[3])) + ((p[4] + p[5]) + (p[6] + p[7]))
             + ((p[8] + p[9]) + (p[10] + p[11])) + ((p[12] + p[13]) + (p[14] + p[15]));
    {
      float a, c; xor32_halves(ps, a, c);
      ps = a + c;                    // == ps + __shfl_xor(ps, 32)
    }
    Lrow = Lrow * scl + ps;
    if (upd) {
#pragma unroll
      for (int r = 0; r < 16; ++r) {
        const float so = __shfl(scl, 4 * g + (r & 3) + 8 * (r >> 2));
#pragma unroll
        for (int cf = 0; cf < 8; ++cf) oacc[cf][r] *= so;
      }
    }
#pragma unroll
    for (int kj = 0; kj < 2; ++kj) {
      union { f16x2 h2; unsigned u; } w0, w1, w2, w3;
      w0.h2 = (f16x2){(_Float16)p[kj * 8 + 0], (_Float16)p[kj * 8 + 1]};
      w1.h2 = (f16x2){(_Float16)p[kj * 8 + 2], (_Float16)p[kj * 8 + 3]};
      w2.h2 = (f16x2){(_Float16)p[kj * 8 + 4], (_Float16)p[kj * 8 + 5]};
      w3.h2 = (f16x2){(_Float16)p[kj * 8 + 6], (_Float16)p[kj * 8 + 7]};
      asm volatile("v_permlane32_swap_b32 %0, %1" : "+v"(w0.u), "+v"(w2.u));
      asm volatile("v_permlane32_swap_b32 %0, %1" : "+v"(w1.u), "+v"(w3.u));
      union { unsigned u[4]; f16x8 v; } pk;
      pk.u[0] = w0.u; pk.u[1] = w1.u; pk.u[2] = w2.u; pk.u[3] = w3.u;
      if (kj == 0) pa0 = pk.v; else pa1 = pk.v;
    }
  };

  // One MFMA-cluster body, parameterized only by the setprio immediates
  // (PHI = prio inside MFMA cluster, PLO = base prio outside). Both h-paths
  // inline the SAME body -> identical fused schedule, only immediates differ.
  auto mfma_cluster = [&](int s, f32x16& s0, f32x16& s1, auto PHI, auto PLO) {
    const int curK = (s & 1) * 32768;
    const int oldV = kVBase + ((s - 1) % 3) * 32768;
    __builtin_amdgcn_s_setprio(decltype(PHI)::value);
#pragma unroll
    for (int kc2 = 0; kc2 < 8; ++kc2) {
      const int c0  = kc2 * 32 + 8 * g;
      const int kj  = kc2 >> 2;                 // 0 for kc2<4, 1 else
      const int cf0 = (2 * kc2) & 7, cf1 = (2 * kc2 + 1) & 7;
      const int jb  = 32 * h + 16 * kj + 8 * g;
      const f16x8 kf0 = *(const f16x8*)(lds + curK + kbl(32 * h + li, c0));
      const f16x8 kf1 = *(const f16x8*)(lds + curK + kbl(32 * h + li, c0 + 16));
      const f16x8 vf0 = *(const f16x8*)(lds + oldV + vbl(32 * cf0 + li, jb));
      const f16x8 vf1 = *(const f16x8*)(lds + oldV + vbl(32 * cf1 + li, jb));
      s0 = __builtin_amdgcn_mfma_f32_32x32x16_f16(kf0, qreg[2 * kc2],     s0, 0, 0, 0);
      s1 = __builtin_amdgcn_mfma_f32_32x32x16_f16(kf1, qreg[2 * kc2 + 1], s1, 0, 0, 0);
      if (kj == 0) {
        oacc[cf0] = __builtin_amdgcn_mfma_f32_32x32x16_f16(pa0, vf0, oacc[cf0], 0, 0, 0);
        oacc[cf1] = __builtin_amdgcn_mfma_f32_32x32x16_f16(pa0, vf1, oacc[cf1], 0, 0, 0);
      } else {
        oacc[cf0] = __builtin_amdgcn_mfma_f32_32x32x16_f16(pa1, vf0, oacc[cf0], 0, 0, 0);
        oacc[cf1] = __builtin_amdgcn_mfma_f32_32x32x16_f16(pa1, vf1, oacc[cf1], 0, 0, 0);
      }
    }
    __builtin_amdgcn_s_setprio(decltype(PLO)::value);
  };

  // ======== peeled step 0: QK only ========
  asm volatile("s_waitcnt vmcnt(0)" ::: "memory");
  __syncthreads();
  // Sibling-asymmetric base priority: SIMD k hosts waves k (h=0) and k+4
  // (h=1). h=1 waves run at base prio 2 (2<->3 around MFMA), h=0 at 0
  // (0<->1). At each post-barrier LDS convoy the h=1 waves win arbitration,
  // pull ahead ~half a convoy, and their MFMA/softmax overlaps the
  // sibling's LDS service. Wave-uniform branch; identical body either way.
  if (h == 1) __builtin_amdgcn_s_setprio(2);
  issue_glds(1);                 // K[1], V[1]: untouched buffers, no hazard
  {
    f32x16 s0, s1;
#pragma unroll
    for (int r = 0; r < 16; ++r) { s0[r] = 0.0f; s1[r] = 0.0f; }
#pragma unroll
    for (int kc2 = 0; kc2 < 8; ++kc2) {
      const int c0 = kc2 * 32 + 8 * g;
      const f16x8 kf0 = *(const f16x8*)(lds + kbl(32 * h + li, c0));
      const f16x8 kf1 = *(const f16x8*)(lds + kbl(32 * h + li, c0 + 16));
      s0 = __builtin_amdgcn_mfma_f32_32x32x16_f16(kf0, qreg[2 * kc2],     s0, 0, 0, 0);
      s1 = __builtin_amdgcn_mfma_f32_32x32x16_f16(kf1, qreg[2 * kc2 + 1], s1, 0, 0, 0);
    }
    softmax_step(s0, s1);
  }

  // ======== main loop s = 1..63: ONE barrier/step, QK(s) ∥ PV(s-1) ========
#pragma unroll 1
  for (int s = 1; s < kSteps; ++s) {
    asm volatile("s_waitcnt vmcnt(0)" ::: "memory");
    __syncthreads();             // tile s resident; buffers (s+1) are >=2 steps dead
    if (s + 1 < kSteps) issue_glds(s + 1);   // early issue: full step covers DMA

    f32x16 s0, s1;
#pragma unroll
    for (int r = 0; r < 16; ++r) { s0[r] = 0.0f; s1[r] = 0.0f; }

    if (h == 1)
      mfma_cluster(s, s0, s1, std::integral_constant<int, 3>{},
                              std::integral_constant<int, 2>{});
    else
      mfma_cluster(s, s0, s1, std::integral_constant<int, 1>{},
                              std::integral_constant<int, 0>{});

    softmax_step(s0, s1);        // overlaps the in-flight glds
  }

  // ======== tail: PV(63) ========
  __builtin_amdgcn_s_setprio(0);   // equalize for tail + epilogue
  {
    const int oldV = kVBase + ((kSteps - 1) % 3) * 32768;
#pragma unroll
    for (int kj = 0; kj < 2; ++kj) {
      const int jb = 32 * h + 16 * kj + 8 * g;
      const f16x8 pf = kj ? pa1 : pa0;
#pragma unroll
      for (int cf = 0; cf < 8; ++cf) {
        const f16x8 vf = *(const f16x8*)(lds + oldV + vbl(32 * cf + li, jb));
        oacc[cf] = __builtin_amdgcn_mfma_f32_32x32x16_f16(pf, vf, oacc[cf], 0, 0, 0);
      }
    }
  }
  __syncthreads();                 // all PV reads done before overlay reuse

  // ======== epilogue: merge j-halves (M,L,O), normalize, add base, store ======
  float* A  = (float*)lds;         // overlay [qw 4][c 256][i 32] f32 = 128KB
  float* Mb = (float*)(lds + MB_OFF);          // [128] (inside V2 region)
  float* Lb = (float*)(lds + LB_OFF);          // [128]
#define AOFF(qw_, c_, i_) \
  ((qw_) * 8192 + (c_) * 32 + (((((i_) >> 2) ^ ((c_) & 7)) << 2) | ((i_) & 3)))

  if (h == 1) {
#pragma unroll
    for (int r = 0; r < 16; ++r) {
      const int iL = 4 * g + (r & 3) + 8 * (r >> 2);
#pragma unroll
      for (int cf = 0; cf < 8; ++cf)
        A[AOFF(qw, 32 * cf + li, iL)] = oacc[cf][r];
    }
    if (g == 0) { Mb[qw * 32 + li] = Mrow; Lb[qw * 32 + li] = Lrow; }
  }
  __syncthreads();
  if (h == 0) {
    const float M1  = Mb[qw * 32 + li];
    const float L1  = Lb[qw * 32 + li];
    const float Mj  = fmaxf(Mrow, M1);
    const float d0  = exp2f((Mrow - Mj) * LOG2E_F);
    const float d1  = exp2f((M1 - Mj) * LOG2E_F);
    const float invL = 1.0f / (Lrow * d0 + L1 * d1);
#pragma unroll
    for (int r = 0; r < 16; ++r) {
      const int iL = 4 * g + (r & 3) + 8 * (r >> 2);
      const float sd0 = __shfl(d0 * invL, iL);
      const float sd1 = __shfl(d1 * invL, iL);
#pragma unroll
      for (int cf = 0; cf < 8; ++cf) {
        const int off = AOFF(qw, 32 * cf + li, iL);
        A[off] = oacc[cf][r] * sd0 + A[off] * sd1;
      }
    }
  }
  __syncthreads();
#undef AOFF
  {
    float* op = outp + ((size_t)b * 512 + dir * 256) * kN;
#pragma unroll
    for (int it = 0; it < 16; ++it) {
      const int n    = it * 512 + tid;
      const int slot = n & 7;           // logical i-chunk
      const int cq   = (n >> 3) & 255;
      const int qw4  = n >> 11;
      const f32x4 ov = *(const f32x4*)(lds + (qw4 * 8192 + cq * 32 +
                                              ((slot ^ (cq & 7)) << 2)) * 4);
      const int col = i0 + qw4 * 32 + slot * 4;
      const float4 bv = *(const float4*)(Qg + (size_t)cq * kN + col);
      float4 r4;
      r4.x = ov[0] + bv.x; r4.y = ov[1] + bv.y;
      r4.z = ov[2] + bv.z; r4.w = ov[3] + bv.w;
      *(float4*)(op + (size_t)cq * kN + col) = r4;
    }
  }
}

extern "C" void kernel_launch(void* const* d_in, const int* in_sizes, int n_in,
                              void* d_out, int out_size, void* d_ws, size_t ws_size,
                              hipStream_t stream) {
  const float* V = (const float*)d_in[0];
  const float* T = (const float*)d_in[1];
  float* out = (float*)d_out;
  char* ws = (char*)d_ws;
  (void)in_sizes; (void)n_in; (void)out_size; (void)ws_size;
  hipLaunchKernelGGL(convert_images, dim3(512), dim3(256), 0, stream, V, T, ws);
  hipLaunchKernelGGL(mutual_attn_fused, dim3(256), dim3(512), 0, stream,
                     V, T, (const char*)ws, out);
}

// Round 15
// 180.836 us; speedup vs baseline: 1.3314x; 1.2140x over previous
//
#include <hip/hip_runtime.h>

typedef _Float16 f16x2 __attribute__((ext_vector_type(2)));
typedef _Float16 f16x4 __attribute__((ext_vector_type(4)));
typedef _Float16 f16x8 __attribute__((ext_vector_type(8)));
typedef float    f32x4 __attribute__((ext_vector_type(4)));
typedef float    f32x16 __attribute__((ext_vector_type(16)));
typedef unsigned uint32x2 __attribute__((ext_vector_type(2)));

#define LOG2E_F 1.44269504088896340736f
#define AS1 __attribute__((address_space(1)))
#define AS3 __attribute__((address_space(3)))

namespace {
constexpr int kC     = 256;
constexpr int kN     = 4096;
constexpr int kQB    = 128;
constexpr int kKVB   = 64;
constexpr int kSteps = kN / kKVB;
constexpr size_t kImgStride = 2097152;   // 2 MB per (b,m) K-image
constexpr size_t kVImgBase  = 16777216;  // V-images at +16 MB
// LDS: K double buffer 2x32K @0 | V TRIPLE buffer 3x32K @64K = 160 KiB exactly.
// Epilogue overlays: A (128K) @0, Mb/Lb inside the V2 region.
constexpr int kVBase  = 65536;
constexpr int MB_OFF  = 131072;
constexpr int LB_OFF  = 131584;
constexpr int LDS_BYTES = 163840;
}

__device__ __forceinline__ int swz8(int r) { return (r ^ (r >> 3)) & 7; }
// K tile: c-major granules: [c8 32][j 64] x 16B. A wave's fragment read
// (li varies, c8 fixed) hits 32 consecutive granules -> conflict-free.
__device__ __forceinline__ int kbl(int j, int c) {
  return (c >> 3) * 1024 + j * 16 + ((c & 7) << 1);
}
// V tile: [c 256][j 64] f16, rows 128 B = 8 slots x 16B (measured conflict-free)
__device__ __forceinline__ int vbl(int c, int j) {
  return c * 128 + ((((j >> 3) ^ swz8(c)) << 4) | ((j & 7) << 1));
}

__device__ __forceinline__ void glds16(const void* g, void* l) {
  __builtin_amdgcn_global_load_lds((AS1 const unsigned int*)g,
                                   (AS3 unsigned int*)l, 16, 0, 0);
}

// xor-32 butterfly halves via the SSA-pure builtin (both post-swap registers).
__device__ __forceinline__ void xor32_halves(float x, float& a, float& c) {
  union { float f; unsigned u; } ux; ux.f = x;
  uint32x2 r = __builtin_amdgcn_permlane32_swap(ux.u, ux.u, false, false);
  union { unsigned u; float f; } ra, rc;
  ra.u = r[0]; rc.u = r[1];
  a = ra.f; c = rc.f;
}

// ============ pre-pass: f32 [C][N] -> pre-swizzled f16 K-image + V-image ======
// Each thread handles 4c x 4j per iter: the c-major kbl granule then takes an
// 8 B f16x4 write (c=cbase..cbase+3 contiguous in the granule) -> 16 b64 K
// LDS-writes per thread instead of 64 scalar b16 (4x fewer, less conflicted).
__global__ __launch_bounds__(256)
void convert_images(const float* __restrict__ Vp, const float* __restrict__ Tp,
                    char* __restrict__ ws) {
  __shared__ alignas(16) char clds[65536];  // K-copy 32K | V-copy 32K
  const int bm   = blockIdx.x >> 6;   // b*2 + m  (m: 0=V, 1=T)
  const int tile = blockIdx.x & 63;
  const int tid  = threadIdx.x;
  const int cq   = tid >> 4;          // c-quad index (0..15)
  const int jf   = (tid & 15) * 4;    // j base (0..60)
  const float* src = ((bm & 1) ? Tp : Vp) + (size_t)(bm >> 1) * kC * kN;

#pragma unroll
  for (int it = 0; it < 4; ++it) {
    const int cbase = it * 64 + cq * 4;
    _Float16 h[4][4];                  // [dc][jj]
#pragma unroll
    for (int dc = 0; dc < 4; ++dc) {
      const int c = cbase + dc;
      const float4 v = *(const float4*)(src + (size_t)c * kN + tile * 64 + jf);
      h[dc][0] = (_Float16)v.x; h[dc][1] = (_Float16)v.y;
      h[dc][2] = (_Float16)v.z; h[dc][3] = (_Float16)v.w;
      f16x4 hv; hv[0] = h[dc][0]; hv[1] = h[dc][1];
      hv[2] = h[dc][2]; hv[3] = h[dc][3];
      *(f16x4*)(clds + 32768 + vbl(c, jf)) = hv;       // V-copy (8B, aligned)
    }
#pragma unroll
    for (int jj = 0; jj < 4; ++jj) {                   // K-copy: c-major b64
      f16x4 kv; kv[0] = h[0][jj]; kv[1] = h[1][jj];
      kv[2] = h[2][jj]; kv[3] = h[3][jj];
      *(f16x4*)(clds + kbl(jf + jj, cbase)) = kv;      // 8B, aligned
    }
  }
  __syncthreads();
  char* kout = ws + (size_t)bm * kImgStride + (size_t)tile * 32768;
  char* vout = ws + kVImgBase + (size_t)bm * kImgStride + (size_t)tile * 32768;
#pragma unroll
  for (int k = 0; k < 8; ++k) {
    const int off = k * 4096 + tid * 16;
    *(uint4*)(kout + off) = *(const uint4*)(clds + off);
    *(uint4*)(vout + off) = *(const uint4*)(clds + 32768 + off);
  }
}

// ============ main fused attention kernel =====================================
__global__ __launch_bounds__(512, 2)
void mutual_attn_fused(const float* __restrict__ Vp,
                       const float* __restrict__ Tp,
                       const char* __restrict__ ws,
                       float* __restrict__ outp) {
  __shared__ alignas(16) char lds[LDS_BYTES];

  const int tid = threadIdx.x;
  const int w   = tid >> 6;
  const int l   = tid & 63;
  const int li  = l & 31;
  const int g   = l >> 5;
  const int qw  = w & 3;        // i-quadrant (32 rows each)
  const int h   = w >> 2;       // j-half owner (32 j each)

  const int bid = blockIdx.x;
  const int dir = bid & 1;
  const int b   = (bid >> 1) & 3;
  const int qt  = bid >> 3;
  const int i0  = qt * kQB;

  const float* Qg = (dir ? Tp : Vp) + (size_t)b * kC * kN;  // base-add source
  const int bmK = b * 2 + (dir ? 0 : 1);
  const int bmQ = b * 2 + (dir ? 1 : 0);
  const char* KimgK = ws + (size_t)bmK * kImgStride;
  const char* VimgK = ws + kVImgBase + (size_t)bmK * kImgStride;
  const char* KimgQ = ws + (size_t)bmQ * kImgStride;

  auto issue_glds = [&](int t) {  // stage tile t: K->K[t&1], V->V[t%3]
    const char* gk = KimgK + (size_t)t * 32768;
    const char* gv = VimgK + (size_t)t * 32768;
    char* lk = lds + (t & 1) * 32768;
    char* lv = lds + kVBase + (t % 3) * 32768;
    const int off0 = w * 4096 + l * 16;
#pragma unroll
    for (int k = 0; k < 4; ++k) {
      glds16(gk + off0 + k * 1024, lk + off0 + k * 1024);
      glds16(gv + off0 + k * 1024, lv + off0 + k * 1024);
    }
  };

  // ---- stage tile 0 (async HW copy), then gather Q into registers
  issue_glds(0);

  const int iq = i0 + 32 * qw + li;
  const char* qsrc = KimgQ + (size_t)(iq >> 6) * 32768;
  const int jq = iq & 63;
  f16x8 qreg[16];
#pragma unroll
  for (int kc = 0; kc < 16; ++kc)
    qreg[kc] = *(const f16x8*)(qsrc + kbl(jq, kc * 16 + 8 * g));

  float Mrow = -1e30f;
  float Lrow = 0.0f;
  f32x16 oacc[8];
#pragma unroll
  for (int cf = 0; cf < 8; ++cf)
#pragma unroll
    for (int r = 0; r < 16; ++r) oacc[cf][r] = 0.0f;

  f16x8 pa0, pa1;   // P fragments of the previous step (consumed next iter)

  auto softmax_step = [&](f32x16& s0, f32x16& s1) {
    float p[16];
#pragma unroll
    for (int r = 0; r < 16; ++r) p[r] = s0[r] + s1[r];
    // v_max3-friendly reduction tree (value-exact vs pairwise)
    float m0 = fmaxf(fmaxf(p[0],  p[1]),  p[2]);
    float m1 = fmaxf(fmaxf(p[3],  p[4]),  p[5]);
    float m2 = fmaxf(fmaxf(p[6],  p[7]),  p[8]);
    float m3 = fmaxf(fmaxf(p[9],  p[10]), p[11]);
    float m4 = fmaxf(fmaxf(p[12], p[13]), p[14]);
    float mt = fmaxf(fmaxf(fmaxf(m0, m1), m2), fmaxf(fmaxf(m3, m4), p[15]));
    {
      float a, c; xor32_halves(mt, a, c);
      mt = fmaxf(a, c);              // == fmaxf(mt, __shfl_xor(mt, 32))
    }
    const bool  upd  = !__all(mt <= Mrow + 8.0f);     // defer-max
    const float Mnew = upd ? fmaxf(Mrow, mt) : Mrow;
    const float scl  = upd ? exp2f((Mrow - Mnew) * LOG2E_F) : 1.0f;
    Mrow = Mnew;
    const float mb = Mnew * LOG2E_F;
#pragma unroll
    for (int r = 0; r < 16; ++r) p[r] = exp2f(p[r] * LOG2E_F - mb);
    float ps = ((p[0] + p[1]) + (p[2] + p[3])) + ((p[4] + p[5]) + (p[6] + p[7]))
             + ((p[8] + p[9]) + (p[10] + p[11])) + ((p[12] + p[13]) + (p[14] + p[15]));
    {
      float a, c; xor32_halves(ps, a, c);
      ps = a + c;                    // == ps + __shfl_xor(ps, 32)
    }
    Lrow = Lrow * scl + ps;
    if (upd) {
#pragma unroll
      for (int r = 0; r < 16; ++r) {
        const float so = __shfl(scl, 4 * g + (r & 3) + 8 * (r >> 2));
#pragma unroll
        for (int cf = 0; cf < 8; ++cf) oacc[cf][r] *= so;
      }
    }
#pragma unroll
    for (int kj = 0; kj < 2; ++kj) {
      union { f16x2 h2; unsigned u; } w0, w1, w2, w3;
      w0.h2 = (f16x2){(_Float16)p[kj * 8 + 0], (_Float16)p[kj * 8 + 1]};
      w1.h2 = (f16x2){(_Float16)p[kj * 8 + 2], (_Float16)p[kj * 8 + 3]};
      w2.h2 = (f16x2){(_Float16)p[kj * 8 + 4], (_Float16)p[kj * 8 + 5]};
      w3.h2 = (f16x2){(_Float16)p[kj * 8 + 6], (_Float16)p[kj * 8 + 7]};
      asm volatile("v_permlane32_swap_b32 %0, %1" : "+v"(w0.u), "+v"(w2.u));
      asm volatile("v_permlane32_swap_b32 %0, %1" : "+v"(w1.u), "+v"(w3.u));
      union { unsigned u[4]; f16x8 v; } pk;
      pk.u[0] = w0.u; pk.u[1] = w1.u; pk.u[2] = w2.u; pk.u[3] = w3.u;
      if (kj == 0) pa0 = pk.v; else pa1 = pk.v;
    }
  };

  // ======== peeled step 0: QK only ========
  asm volatile("s_waitcnt vmcnt(0)" ::: "memory");
  __syncthreads();
  issue_glds(1);                 // K[1], V[1]: untouched buffers, no hazard
  {
    f32x16 s0, s1;
#pragma unroll
    for (int r = 0; r < 16; ++r) { s0[r] = 0.0f; s1[r] = 0.0f; }
#pragma unroll
    for (int kc2 = 0; kc2 < 8; ++kc2) {
      const int c0 = kc2 * 32 + 8 * g;
      const f16x8 kf0 = *(const f16x8*)(lds + kbl(32 * h + li, c0));
      const f16x8 kf1 = *(const f16x8*)(lds + kbl(32 * h + li, c0 + 16));
      s0 = __builtin_amdgcn_mfma_f32_32x32x16_f16(kf0, qreg[2 * kc2],     s0, 0, 0, 0);
      s1 = __builtin_amdgcn_mfma_f32_32x32x16_f16(kf1, qreg[2 * kc2 + 1], s1, 0, 0, 0);
    }
    softmax_step(s0, s1);
  }

  // ======== main loop s = 1..63: ONE barrier/step, QK(s) ∥ PV(s-1) ========
#pragma unroll 1
  for (int s = 1; s < kSteps; ++s) {
    asm volatile("s_waitcnt vmcnt(0)" ::: "memory");
    __syncthreads();             // tile s resident; buffers (s+1) are >=2 steps dead
    if (s + 1 < kSteps) issue_glds(s + 1);   // early issue: full step covers DMA

    const int curK = (s & 1) * 32768;
    const int oldV = kVBase + ((s - 1) % 3) * 32768;

    f32x16 s0, s1;
#pragma unroll
    for (int r = 0; r < 16; ++r) { s0[r] = 0.0f; s1[r] = 0.0f; }

    __builtin_amdgcn_s_setprio(1);
#pragma unroll
    for (int kc2 = 0; kc2 < 8; ++kc2) {
      const int c0  = kc2 * 32 + 8 * g;
      const int kj  = kc2 >> 2;                 // 0 for kc2<4, 1 else
      const int cf0 = (2 * kc2) & 7, cf1 = (2 * kc2 + 1) & 7;
      const int jb  = 32 * h + 16 * kj + 8 * g;
      const f16x8 kf0 = *(const f16x8*)(lds + curK + kbl(32 * h + li, c0));
      const f16x8 kf1 = *(const f16x8*)(lds + curK + kbl(32 * h + li, c0 + 16));
      const f16x8 vf0 = *(const f16x8*)(lds + oldV + vbl(32 * cf0 + li, jb));
      const f16x8 vf1 = *(const f16x8*)(lds + oldV + vbl(32 * cf1 + li, jb));
      s0 = __builtin_amdgcn_mfma_f32_32x32x16_f16(kf0, qreg[2 * kc2],     s0, 0, 0, 0);
      s1 = __builtin_amdgcn_mfma_f32_32x32x16_f16(kf1, qreg[2 * kc2 + 1], s1, 0, 0, 0);
      if (kj == 0) {
        oacc[cf0] = __builtin_amdgcn_mfma_f32_32x32x16_f16(pa0, vf0, oacc[cf0], 0, 0, 0);
        oacc[cf1] = __builtin_amdgcn_mfma_f32_32x32x16_f16(pa0, vf1, oacc[cf1], 0, 0, 0);
      } else {
        oacc[cf0] = __builtin_amdgcn_mfma_f32_32x32x16_f16(pa1, vf0, oacc[cf0], 0, 0, 0);
        oacc[cf1] = __builtin_amdgcn_mfma_f32_32x32x16_f16(pa1, vf1, oacc[cf1], 0, 0, 0);
      }
    }
    __builtin_amdgcn_s_setprio(0);

    softmax_step(s0, s1);        // overlaps the in-flight glds
  }

  // ======== tail: PV(63) ========
  {
    const int oldV = kVBase + ((kSteps - 1) % 3) * 32768;
#pragma unroll
    for (int kj = 0; kj < 2; ++kj) {
      const int jb = 32 * h + 16 * kj + 8 * g;
      const f16x8 pf = kj ? pa1 : pa0;
#pragma unroll
      for (int cf = 0; cf < 8; ++cf) {
        const f16x8 vf = *(const f16x8*)(lds + oldV + vbl(32 * cf + li, jb));
        oacc[cf] = __builtin_amdgcn_mfma_f32_32x32x16_f16(pf, vf, oacc[cf], 0, 0, 0);
      }
    }
  }
  __syncthreads();                 // all PV reads done before overlay reuse

  // ======== epilogue: merge j-halves (M,L,O), normalize, add base, store ======
  float* A  = (float*)lds;         // overlay [qw 4][c 256][i 32] f32 = 128KB
  float* Mb = (float*)(lds + MB_OFF);          // [128] (inside V2 region)
  float* Lb = (float*)(lds + LB_OFF);          // [128]
#define AOFF(qw_, c_, i_) \
  ((qw_) * 8192 + (c_) * 32 + (((((i_) >> 2) ^ ((c_) & 7)) << 2) | ((i_) & 3)))

  if (h == 1) {
#pragma unroll
    for (int r = 0; r < 16; ++r) {
      const int iL = 4 * g + (r & 3) + 8 * (r >> 2);
#pragma unroll
      for (int cf = 0; cf < 8; ++cf)
        A[AOFF(qw, 32 * cf + li, iL)] = oacc[cf][r];
    }
    if (g == 0) { Mb[qw * 32 + li] = Mrow; Lb[qw * 32 + li] = Lrow; }
  }
  __syncthreads();
  if (h == 0) {
    const float M1  = Mb[qw * 32 + li];
    const float L1  = Lb[qw * 32 + li];
    const float Mj  = fmaxf(Mrow, M1);
    const float d0  = exp2f((Mrow - Mj) * LOG2E_F);
    const float d1  = exp2f((M1 - Mj) * LOG2E_F);
    const float invL = 1.0f / (Lrow * d0 + L1 * d1);
#pragma unroll
    for (int r = 0; r < 16; ++r) {
      const int iL = 4 * g + (r & 3) + 8 * (r >> 2);
      const float sd0 = __shfl(d0 * invL, iL);
      const float sd1 = __shfl(d1 * invL, iL);
#pragma unroll
      for (int cf = 0; cf < 8; ++cf) {
        const int off = AOFF(qw, 32 * cf + li, iL);
        A[off] = oacc[cf][r] * sd0 + A[off] * sd1;
      }
    }
  }
  __syncthreads();
#undef AOFF
  {
    float* op = outp + ((size_t)b * 512 + dir * 256) * kN;
#pragma unroll
    for (int it = 0; it < 16; ++it) {
      const int n    = it * 512 + tid;
      const int slot = n & 7;           // logical i-chunk
      const int cq   = (n >> 3) & 255;
      const int qw4  = n >> 11;
      const f32x4 ov = *(const f32x4*)(lds + (qw4 * 8192 + cq * 32 +
                                              ((slot ^ (cq & 7)) << 2)) * 4);
      const int col = i0 + qw4 * 32 + slot * 4;
      const float4 bv = *(const float4*)(Qg + (size_t)cq * kN + col);
      float4 r4;
      r4.x = ov[0] + bv.x; r4.y = ov[1] + bv.y;
      r4.z = ov[2] + bv.z; r4.w = ov[3] + bv.w;
      *(float4*)(op + (size_t)cq * kN + col) = r4;
    }
  }
}

extern "C" void kernel_launch(void* const* d_in, const int* in_sizes, int n_in,
                              void* d_out, int out_size, void* d_ws, size_t ws_size,
                              hipStream_t stream) {
  const float* V = (const float*)d_in[0];
  const float* T = (const float*)d_in[1];
  float* out = (float*)d_out;
  char* ws = (char*)d_ws;
  (void)in_sizes; (void)n_in; (void)out_size; (void)ws_size;
  hipLaunchKernelGGL(convert_images, dim3(512), dim3(256), 0, stream, V, T, ws);
  hipLaunchKernelGGL(mutual_attn_fused, dim3(256), dim3(512), 0, stream,
                     V, T, (const char*)ws, out);
}